// Round 4
// baseline (623.078 us; speedup 1.0000x reference)
//
#include <hip/hip_runtime.h>
#include <hip/hip_bf16.h>

#define SEQ   512
#define BATCH 256
#define EMB   200
#define HID   50
#define G3    150     // 3*HID
#define MLPN  100

typedef __attribute__((ext_vector_type(8))) short bf16x8;
typedef __attribute__((ext_vector_type(4))) float f32x4;

__device__ __forceinline__ unsigned short f2bf(float x) {
    unsigned u = __float_as_uint(x);
    unsigned r = (u + 0x7FFFu + ((u >> 16) & 1u)) >> 16;   // RNE
    return (unsigned short)r;
}

#define GLOAD_LDS16(g, s) __builtin_amdgcn_global_load_lds( \
    (const __attribute__((address_space(1))) void*)(g),     \
    (__attribute__((address_space(3))) void*)(s), 16, 0, 0)

// ---------------------------------------------------------------------------
// k0: convert Wih_f/Wih_b fp32 -> bf16 into padded layout Wpad[320][224]
// ---------------------------------------------------------------------------
__global__ __launch_bounds__(256) void k0_wpad(
    const float* __restrict__ Wih_f, const float* __restrict__ Wih_b,
    unsigned short* __restrict__ Wpad)
{
    int idx = blockIdx.x * 256 + threadIdx.x;
    if (idx >= 320 * 224) return;
    int row = idx / 224;
    int k   = idx - row * 224;
    int d   = row / 160;
    int r   = row - d * 160;
    float v = 0.f;
    if (r < G3 && k < EMB) v = (d ? Wih_b : Wih_f)[r * EMB + k];
    Wpad[idx] = f2bf(v);
}

// ---------------------------------------------------------------------------
// k1: gx = emb[tok] @ [Wih_f;Wih_b].T + bias, via bf16 MFMA 16x16x32.
// ---------------------------------------------------------------------------
__global__ __launch_bounds__(256) void k1_gx(
    const int* __restrict__ tokens, const float* __restrict__ emb,
    const unsigned short* __restrict__ Wpad,
    const float* __restrict__ bih_f, const float* __restrict__ bih_b,
    float* __restrict__ gx)
{
    __shared__ unsigned short Abuf[64 * 32];    // 4 KB
    __shared__ unsigned short Bbuf[320 * 32];   // 20 KB
    __shared__ float bias[320];
    __shared__ int tok[64];

    const int t = threadIdx.x;
    const int w = t >> 6;
    const int l = t & 63;
    const long row0 = (long)blockIdx.x * 64;

    for (int idx = t; idx < 320; idx += 256) {
        int d = idx / 160, r = idx - d * 160;
        bias[idx] = (r < G3) ? (d ? bih_b[r] : bih_f[r]) : 0.f;
    }
    if (t < 64) tok[t] = tokens[row0 + t];

    f32x4 acc[20];
    #pragma unroll
    for (int nt = 0; nt < 20; nt++) acc[nt] = (f32x4){0.f, 0.f, 0.f, 0.f};

    const int ar = t >> 2;
    const int kq = t & 3;
    __syncthreads();

    for (int c = 0; c < 7; c++) {
        const int kc0 = c * 32;
        float4 v0 = {0,0,0,0}, v1 = {0,0,0,0};
        if (kc0 + kq * 8 < EMB) {
            const float* src = emb + (long)tok[ar] * EMB + kc0 + kq * 8;
            v0 = *reinterpret_cast<const float4*>(src);
            v1 = *reinterpret_cast<const float4*>(src + 4);
        }
        __syncthreads();
        unsigned p0 = f2bf(v0.x) | ((unsigned)f2bf(v0.y) << 16);
        unsigned p1 = f2bf(v0.z) | ((unsigned)f2bf(v0.w) << 16);
        unsigned p2 = f2bf(v1.x) | ((unsigned)f2bf(v1.y) << 16);
        unsigned p3 = f2bf(v1.z) | ((unsigned)f2bf(v1.w) << 16);
        *reinterpret_cast<uint2*>(&Abuf[ar * 32 + kq * 8])     = make_uint2(p0, p1);
        *reinterpret_cast<uint2*>(&Abuf[ar * 32 + kq * 8 + 4]) = make_uint2(p2, p3);
        #pragma unroll
        for (int q = 0; q < 5; q++) {
            const int rbase = w * 80 + q * 16;
            const int rb = rbase + (l >> 2);
            const unsigned short* gsrc = Wpad + (long)rb * 224 + kc0 + (l & 3) * 8;
            GLOAD_LDS16(gsrc, &Bbuf[rbase * 32]);
        }
        __syncthreads();
        bf16x8 af = *reinterpret_cast<bf16x8*>(&Abuf[(w * 16 + (l & 15)) * 32 + (l >> 4) * 8]);
        #pragma unroll
        for (int nt = 0; nt < 20; nt++) {
            bf16x8 bfr = *reinterpret_cast<bf16x8*>(&Bbuf[(nt * 16 + (l & 15)) * 32 + (l >> 4) * 8]);
            acc[nt] = __builtin_amdgcn_mfma_f32_16x16x32_bf16(af, bfr, acc[nt], 0, 0, 0);
        }
    }

    const int colL  = l & 15;
    const int rquad = l >> 4;
    #pragma unroll
    for (int nt = 0; nt < 20; nt++) {
        int pcol = nt * 16 + colL;
        int d = pcol / 160;
        int jc = pcol - d * 160;
        if (jc >= G3) continue;
        float bv = bias[pcol];
        long col = d * G3 + jc;
        #pragma unroll
        for (int i = 0; i < 4; i++) {
            long row = row0 + w * 16 + rquad * 4 + i;
            gx[row * 300 + col] = acc[nt][i] + bv;
        }
    }
}

// ---------------------------------------------------------------------------
// k2: GRU scan — ONE WAVE per (batch, direction). No LDS, no barriers.
// Lane l<50 owns rows {l, l+50, l+100} of Whh in arch VGPRs (150 floats).
// h[k] broadcast via v_readlane -> SGPR -> v_fmac_f32 v,s,v (1 SGPR/instr ok).
// gx prefetched 2 steps ahead.
// ---------------------------------------------------------------------------
#define K2_LOAD(S, VR, VZ, VN) do {                                        \
    int t_ = dir ? (SEQ - 1 - (S)) : (S);                                  \
    const float* p_ = gx + (long)t_ * (BATCH * 300) + base;                \
    VR = p_[0]; VZ = p_[50]; VN = p_[100];                                 \
} while (0)

#define K2_STEP(S, VR, VZ, VN) do {                                        \
    int t_ = dir ? (SEQ - 1 - (S)) : (S);                                  \
    float gxr_ = VR, gxz_ = VZ, gxn_ = VN;                                 \
    if ((S) + 2 < SEQ) K2_LOAD((S) + 2, VR, VZ, VN);                       \
    float ar_ = br, az_ = bz, an_ = bn;                                    \
    _Pragma("unroll")                                                      \
    for (int k_ = 0; k_ < HID; k_++) {                                     \
        float hk_ = __int_as_float(                                        \
            __builtin_amdgcn_readlane(__float_as_int(hold), k_));          \
        ar_ = fmaf(wr[k_], hk_, ar_);                                      \
        az_ = fmaf(wz[k_], hk_, az_);                                      \
        an_ = fmaf(wn[k_], hk_, an_);                                      \
    }                                                                      \
    float r_ = 1.f / (1.f + __expf(-(gxr_ + ar_)));                        \
    float z_ = 1.f / (1.f + __expf(-(gxz_ + az_)));                        \
    float x_ = gxn_ + r_ * an_;                                            \
    float e2_ = __expf(-2.f * x_);                                         \
    float n_ = (1.f - e2_) / (1.f + e2_);                                  \
    hold = (1.f - z_) * n_ + z_ * hold;                                    \
    if (act) h[((long)t_ * BATCH + b) * 100 + dir * HID + l] = hold;       \
} while (0)

__global__ __launch_bounds__(64, 1) void k2_gru(
    const float* __restrict__ gx,
    const float* __restrict__ Whh_f, const float* __restrict__ bhh_f,
    const float* __restrict__ Whh_b, const float* __restrict__ bhh_b,
    float* __restrict__ h)
{
    const int b   = blockIdx.x & 255;
    const int dir = blockIdx.x >> 8;
    const float* __restrict__ Whh = dir ? Whh_b : Whh_f;
    const float* __restrict__ bhh = dir ? bhh_b : bhh_f;
    const int l = threadIdx.x;
    const bool act = (l < HID);
    const int lc = act ? l : (HID - 1);    // clamped lane for safe addresses

    float wr[HID], wz[HID], wn[HID];
    float br = 0.f, bz = 0.f, bn = 0.f;

    if (act) {
        br = bhh[l]; bz = bhh[l + HID]; bn = bhh[l + 2 * HID];
        #pragma unroll
        for (int k = 0; k < HID; k++) {
            wr[k] = Whh[l * HID + k];
            wz[k] = Whh[(l + HID) * HID + k];
            wn[k] = Whh[(l + 2 * HID) * HID + k];
        }
    } else {
        #pragma unroll
        for (int k = 0; k < HID; k++) { wr[k] = 0.f; wz[k] = 0.f; wn[k] = 0.f; }
    }

    const long base = (long)b * 300 + dir * G3 + lc;
    float hold = 0.f;
    float p0r, p0z, p0n, p1r, p1z, p1n;
    K2_LOAD(0, p0r, p0z, p0n);
    K2_LOAD(1, p1r, p1z, p1n);

    for (int s = 0; s < SEQ; s += 2) {
        K2_STEP(s,     p0r, p0z, p0n);
        K2_STEP(s + 1, p1r, p1z, p1n);
    }
}

// ---------------------------------------------------------------------------
// k3: scores via thread-per-row; W_mlp in LDS, h row in registers.
// ---------------------------------------------------------------------------
__global__ __launch_bounds__(256) void k3_scores(
    const float* __restrict__ h, const float* __restrict__ W_mlp,
    const float* __restrict__ b_mlp, const float* __restrict__ ctx,
    float* __restrict__ scT)
{
    __shared__ float4 Wm[MLPN * 25];
    __shared__ float bm[MLPN], cx[MLPN];
    const int tid = threadIdx.x;
    for (int idx = tid; idx < MLPN * 25; idx += 256)
        Wm[idx] = reinterpret_cast<const float4*>(W_mlp)[idx];
    if (tid < MLPN) { bm[tid] = b_mlp[tid]; cx[tid] = ctx[tid]; }
    __syncthreads();

    const long row = (long)blockIdx.x * 256 + tid;
    float4 hr[25];
    const float4* hp = reinterpret_cast<const float4*>(h + row * 100);
    #pragma unroll
    for (int i = 0; i < 25; i++) hr[i] = hp[i];

    float s = 0.f;
    for (int jj = 0; jj < MLPN; jj++) {
        float acc = bm[jj];
        #pragma unroll
        for (int i = 0; i < 25; i++) {
            float4 wv = Wm[jj * 25 + i];
            acc += wv.x * hr[i].x + wv.y * hr[i].y + wv.z * hr[i].z + wv.w * hr[i].w;
        }
        float e2 = __expf(-2.f * acc);
        float u = (1.f - e2) / (1.f + e2);
        s += u * cx[jj];
    }
    const int t = (int)(row >> 8);
    const int b = (int)(row & 255);
    scT[(long)b * SEQ + t] = s;
}

// ---------------------------------------------------------------------------
// k4: per-batch softmax over t, then doc[b][i] = sum_t alpha[t]*h[t][b][i]
// ---------------------------------------------------------------------------
__global__ __launch_bounds__(128) void k4_doc(
    const float* __restrict__ h, const float* __restrict__ scT,
    float* __restrict__ out)
{
    const int b = blockIdx.x;
    const int tid = threadIdx.x;
    __shared__ float al[SEQ];
    __shared__ float red[128];

    float4 sv = reinterpret_cast<const float4*>(scT + (long)b * SEQ)[tid];
    float m = fmaxf(fmaxf(sv.x, sv.y), fmaxf(sv.z, sv.w));
    red[tid] = m;
    __syncthreads();
    if (tid < 64) red[tid] = fmaxf(red[tid], red[tid + 64]);
    __syncthreads();
    if (tid < 64) {
        float v = red[tid];
        for (int o = 32; o > 0; o >>= 1) v = fmaxf(v, __shfl_down(v, o));
        if (tid == 0) red[0] = v;
    }
    __syncthreads();
    m = red[0];
    float e0 = __expf(sv.x - m), e1 = __expf(sv.y - m);
    float e2 = __expf(sv.z - m), e3 = __expf(sv.w - m);
    float psum = e0 + e1 + e2 + e3;
    __syncthreads();
    red[tid] = psum;
    __syncthreads();
    if (tid < 64) red[tid] += red[tid + 64];
    __syncthreads();
    if (tid < 64) {
        float v = red[tid];
        for (int o = 32; o > 0; o >>= 1) v += __shfl_down(v, o);
        if (tid == 0) red[0] = v;
    }
    __syncthreads();
    const float inv = 1.f / red[0];
    al[tid * 4 + 0] = e0 * inv;
    al[tid * 4 + 1] = e1 * inv;
    al[tid * 4 + 2] = e2 * inv;
    al[tid * 4 + 3] = e3 * inv;
    __syncthreads();

    if (tid < MLPN) {
        float acc = 0.f;
        for (int t = 0; t < SEQ; t++)
            acc += al[t] * h[((long)t * BATCH + b) * 100 + tid];
        out[(long)b * 100 + tid] = acc;
    }
}

// ---------------------------------------------------------------------------
extern "C" void kernel_launch(void* const* d_in, const int* in_sizes, int n_in,
                              void* d_out, int out_size, void* d_ws, size_t ws_size,
                              hipStream_t stream)
{
    const int*   tokens = (const int*)d_in[0];
    const float* emb    = (const float*)d_in[1];
    const float* Wih_f  = (const float*)d_in[2];
    const float* Whh_f  = (const float*)d_in[3];
    const float* bih_f  = (const float*)d_in[4];
    const float* bhh_f  = (const float*)d_in[5];
    const float* Wih_b  = (const float*)d_in[6];
    const float* Whh_b  = (const float*)d_in[7];
    const float* bih_b  = (const float*)d_in[8];
    const float* bhh_b  = (const float*)d_in[9];
    const float* W_mlp  = (const float*)d_in[10];
    const float* b_mlp  = (const float*)d_in[11];
    const float* ctx    = (const float*)d_in[12];
    float* out = (float*)d_out;

    float* gx  = (float*)d_ws;                         // SEQ*BATCH*300
    float* h   = gx + (size_t)SEQ * BATCH * 300;       // SEQ*BATCH*100
    float* scT = h  + (size_t)SEQ * BATCH * 100;       // BATCH*SEQ
    unsigned short* Wpad = (unsigned short*)scT;       // aliased, dead before k3

    k0_wpad<<<280, 256, 0, stream>>>(Wih_f, Wih_b, Wpad);
    k1_gx<<<2048, 256, 0, stream>>>(tokens, emb, Wpad, bih_f, bih_b, gx);
    k2_gru<<<512, 64, 0, stream>>>(gx, Whh_f, bhh_f, Whh_b, bhh_b, h);
    k3_scores<<<512, 256, 0, stream>>>(h, W_mlp, b_mlp, ctx, scT);
    k4_doc<<<256, 128, 0, stream>>>(h, scT, out);
}

// Round 5
// 621.405 us; speedup vs baseline: 1.0027x; 1.0027x over previous
//
#include <hip/hip_runtime.h>
#include <hip/hip_bf16.h>

#define SEQ   512
#define BATCH 256
#define EMB   200
#define HID   50
#define G3    150     // 3*HID
#define MLPN  100

typedef __attribute__((ext_vector_type(8))) short bf16x8;
typedef __attribute__((ext_vector_type(4))) float f32x4;
typedef __attribute__((ext_vector_type(16))) float f32x16;

__device__ __forceinline__ unsigned short f2bf(float x) {
    unsigned u = __float_as_uint(x);
    unsigned r = (u + 0x7FFFu + ((u >> 16) & 1u)) >> 16;   // RNE
    return (unsigned short)r;
}

#define GLOAD_LDS16(g, s) __builtin_amdgcn_global_load_lds( \
    (const __attribute__((address_space(1))) void*)(g),     \
    (__attribute__((address_space(3))) void*)(s), 16, 0, 0)

// ---------------------------------------------------------------------------
// k0: convert Wih_f/Wih_b fp32 -> bf16 into padded layout Wpad[320][224]
// ---------------------------------------------------------------------------
__global__ __launch_bounds__(256) void k0_wpad(
    const float* __restrict__ Wih_f, const float* __restrict__ Wih_b,
    unsigned short* __restrict__ Wpad)
{
    int idx = blockIdx.x * 256 + threadIdx.x;
    if (idx >= 320 * 224) return;
    int row = idx / 224;
    int k   = idx - row * 224;
    int d   = row / 160;
    int r   = row - d * 160;
    float v = 0.f;
    if (r < G3 && k < EMB) v = (d ? Wih_b : Wih_f)[r * EMB + k];
    Wpad[idx] = f2bf(v);
}

// ---------------------------------------------------------------------------
// k1: gx = emb[tok] @ [Wih_f;Wih_b].T + bias, via bf16 MFMA 16x16x32.
// ---------------------------------------------------------------------------
__global__ __launch_bounds__(256) void k1_gx(
    const int* __restrict__ tokens, const float* __restrict__ emb,
    const unsigned short* __restrict__ Wpad,
    const float* __restrict__ bih_f, const float* __restrict__ bih_b,
    float* __restrict__ gx)
{
    __shared__ unsigned short Abuf[64 * 32];    // 4 KB
    __shared__ unsigned short Bbuf[320 * 32];   // 20 KB
    __shared__ float bias[320];
    __shared__ int tok[64];

    const int t = threadIdx.x;
    const int w = t >> 6;
    const int l = t & 63;
    const long row0 = (long)blockIdx.x * 64;

    for (int idx = t; idx < 320; idx += 256) {
        int d = idx / 160, r = idx - d * 160;
        bias[idx] = (r < G3) ? (d ? bih_b[r] : bih_f[r]) : 0.f;
    }
    if (t < 64) tok[t] = tokens[row0 + t];

    f32x4 acc[20];
    #pragma unroll
    for (int nt = 0; nt < 20; nt++) acc[nt] = (f32x4){0.f, 0.f, 0.f, 0.f};

    const int ar = t >> 2;
    const int kq = t & 3;
    __syncthreads();

    for (int c = 0; c < 7; c++) {
        const int kc0 = c * 32;
        float4 v0 = {0,0,0,0}, v1 = {0,0,0,0};
        if (kc0 + kq * 8 < EMB) {
            const float* src = emb + (long)tok[ar] * EMB + kc0 + kq * 8;
            v0 = *reinterpret_cast<const float4*>(src);
            v1 = *reinterpret_cast<const float4*>(src + 4);
        }
        __syncthreads();
        unsigned p0 = f2bf(v0.x) | ((unsigned)f2bf(v0.y) << 16);
        unsigned p1 = f2bf(v0.z) | ((unsigned)f2bf(v0.w) << 16);
        unsigned p2 = f2bf(v1.x) | ((unsigned)f2bf(v1.y) << 16);
        unsigned p3 = f2bf(v1.z) | ((unsigned)f2bf(v1.w) << 16);
        *reinterpret_cast<uint2*>(&Abuf[ar * 32 + kq * 8])     = make_uint2(p0, p1);
        *reinterpret_cast<uint2*>(&Abuf[ar * 32 + kq * 8 + 4]) = make_uint2(p2, p3);
        #pragma unroll
        for (int q = 0; q < 5; q++) {
            const int rbase = w * 80 + q * 16;
            const int rb = rbase + (l >> 2);
            const unsigned short* gsrc = Wpad + (long)rb * 224 + kc0 + (l & 3) * 8;
            GLOAD_LDS16(gsrc, &Bbuf[rbase * 32]);
        }
        __syncthreads();
        bf16x8 af = *reinterpret_cast<bf16x8*>(&Abuf[(w * 16 + (l & 15)) * 32 + (l >> 4) * 8]);
        #pragma unroll
        for (int nt = 0; nt < 20; nt++) {
            bf16x8 bfr = *reinterpret_cast<bf16x8*>(&Bbuf[(nt * 16 + (l & 15)) * 32 + (l >> 4) * 8]);
            acc[nt] = __builtin_amdgcn_mfma_f32_16x16x32_bf16(af, bfr, acc[nt], 0, 0, 0);
        }
    }

    const int colL  = l & 15;
    const int rquad = l >> 4;
    #pragma unroll
    for (int nt = 0; nt < 20; nt++) {
        int pcol = nt * 16 + colL;
        int d = pcol / 160;
        int jc = pcol - d * 160;
        if (jc >= G3) continue;
        float bv = bias[pcol];
        long col = d * G3 + jc;
        #pragma unroll
        for (int i = 0; i < 4; i++) {
            long row = row0 + w * 16 + rquad * 4 + i;
            gx[row * 300 + col] = acc[nt][i] + bv;
        }
    }
}

// ---------------------------------------------------------------------------
// k2: GRU scan — ONE WAVE per (batch, direction). No LDS, no barriers.
// Weights live in named f32x16 SSA vectors (only constant subscripts) so the
// allocator cannot dump them to scratch; amdgpu_waves_per_eu(1,1) gives the
// full VGPR file. Uniform control flow (lanes >=50 compute junk on clamped
// row 49; readlane never reads them; stores guarded).
// ---------------------------------------------------------------------------
#define K2_RL(K) __int_as_float(__builtin_amdgcn_readlane(__float_as_int(hold), (K)))

#define K2_C16(WR, WZ, WN, B)                                              \
    _Pragma("unroll")                                                      \
    for (int k_ = 0; k_ < 16; k_++) {                                      \
        const float hk_ = K2_RL((B) + k_);                                 \
        ar_ = fmaf(WR[k_], hk_, ar_);                                      \
        az_ = fmaf(WZ[k_], hk_, az_);                                      \
        an_ = fmaf(WN[k_], hk_, an_);                                      \
    }

#define K2_LOAD(S, VR, VZ, VN) do {                                        \
    int t_ = dir ? (SEQ - 1 - (S)) : (S);                                  \
    const float* p_ = gx + (long)t_ * (BATCH * 300) + base;                \
    VR = p_[0]; VZ = p_[50]; VN = p_[100];                                 \
} while (0)

#define K2_STEP(S, VR, VZ, VN) do {                                        \
    const int t_ = dir ? (SEQ - 1 - (S)) : (S);                            \
    const float gxr_ = VR, gxz_ = VZ, gxn_ = VN;                           \
    if ((S) + 2 < SEQ) K2_LOAD((S) + 2, VR, VZ, VN);                       \
    float ar_ = br, az_ = bz, an_ = bn;                                    \
    K2_C16(wr0, wz0, wn0, 0)                                               \
    K2_C16(wr1, wz1, wn1, 16)                                              \
    K2_C16(wr2, wz2, wn2, 32)                                              \
    {                                                                      \
        const float h48_ = K2_RL(48);                                      \
        const float h49_ = K2_RL(49);                                      \
        ar_ = fmaf(wr48, h48_, ar_); az_ = fmaf(wz48, h48_, az_);          \
        an_ = fmaf(wn48, h48_, an_);                                       \
        ar_ = fmaf(wr49, h49_, ar_); az_ = fmaf(wz49, h49_, az_);          \
        an_ = fmaf(wn49, h49_, an_);                                       \
    }                                                                      \
    const float r_ = 1.f / (1.f + __expf(-(gxr_ + ar_)));                  \
    const float z_ = 1.f / (1.f + __expf(-(gxz_ + az_)));                  \
    const float x_ = gxn_ + r_ * an_;                                      \
    const float e2_ = __expf(-2.f * x_);                                   \
    const float n_ = (1.f - e2_) / (1.f + e2_);                            \
    hold = (1.f - z_) * n_ + z_ * hold;                                    \
    if (act) h[((long)t_ * BATCH + b) * 100 + dir * HID + l] = hold;       \
} while (0)

__global__ __launch_bounds__(64)
__attribute__((amdgpu_waves_per_eu(1, 1)))
void k2_gru(
    const float* __restrict__ gx,
    const float* __restrict__ Whh_f, const float* __restrict__ bhh_f,
    const float* __restrict__ Whh_b, const float* __restrict__ bhh_b,
    float* __restrict__ h)
{
    const int b   = blockIdx.x & 255;
    const int dir = blockIdx.x >> 8;
    const float* __restrict__ Whh = dir ? Whh_b : Whh_f;
    const float* __restrict__ bhh = dir ? bhh_b : bhh_f;
    const int l = threadIdx.x;
    const bool act = (l < HID);
    const int lc = act ? l : (HID - 1);    // clamp: uniform control flow

    const float* Wr = Whh + (long)lc * HID;
    const float* Wz = Whh + (long)(lc + HID) * HID;
    const float* Wn = Whh + (long)(lc + 2 * HID) * HID;

    f32x16 wr0, wr1, wr2, wz0, wz1, wz2, wn0, wn1, wn2;
    #pragma unroll
    for (int k = 0; k < 16; k++) {
        wr0[k] = Wr[k];      wz0[k] = Wz[k];      wn0[k] = Wn[k];
        wr1[k] = Wr[16 + k]; wz1[k] = Wz[16 + k]; wn1[k] = Wn[16 + k];
        wr2[k] = Wr[32 + k]; wz2[k] = Wz[32 + k]; wn2[k] = Wn[32 + k];
    }
    const float wr48 = Wr[48], wr49 = Wr[49];
    const float wz48 = Wz[48], wz49 = Wz[49];
    const float wn48 = Wn[48], wn49 = Wn[49];
    const float br = bhh[lc], bz = bhh[lc + HID], bn = bhh[lc + 2 * HID];

    const long base = (long)b * 300 + dir * G3 + lc;
    float hold = 0.f;
    float p0r, p0z, p0n, p1r, p1z, p1n;
    K2_LOAD(0, p0r, p0z, p0n);
    K2_LOAD(1, p1r, p1z, p1n);

    for (int s = 0; s < SEQ; s += 2) {
        K2_STEP(s,     p0r, p0z, p0n);
        K2_STEP(s + 1, p1r, p1z, p1n);
    }
}

// ---------------------------------------------------------------------------
// k3: scores via thread-per-row; W_mlp in LDS, h row in registers.
// ---------------------------------------------------------------------------
__global__ __launch_bounds__(256) void k3_scores(
    const float* __restrict__ h, const float* __restrict__ W_mlp,
    const float* __restrict__ b_mlp, const float* __restrict__ ctx,
    float* __restrict__ scT)
{
    __shared__ float4 Wm[MLPN * 25];
    __shared__ float bm[MLPN], cx[MLPN];
    const int tid = threadIdx.x;
    for (int idx = tid; idx < MLPN * 25; idx += 256)
        Wm[idx] = reinterpret_cast<const float4*>(W_mlp)[idx];
    if (tid < MLPN) { bm[tid] = b_mlp[tid]; cx[tid] = ctx[tid]; }
    __syncthreads();

    const long row = (long)blockIdx.x * 256 + tid;
    float4 hr[25];
    const float4* hp = reinterpret_cast<const float4*>(h + row * 100);
    #pragma unroll
    for (int i = 0; i < 25; i++) hr[i] = hp[i];

    float s = 0.f;
    for (int jj = 0; jj < MLPN; jj++) {
        float acc = bm[jj];
        #pragma unroll
        for (int i = 0; i < 25; i++) {
            float4 wv = Wm[jj * 25 + i];
            acc += wv.x * hr[i].x + wv.y * hr[i].y + wv.z * hr[i].z + wv.w * hr[i].w;
        }
        float e2 = __expf(-2.f * acc);
        float u = (1.f - e2) / (1.f + e2);
        s += u * cx[jj];
    }
    const int t = (int)(row >> 8);
    const int b = (int)(row & 255);
    scT[(long)b * SEQ + t] = s;
}

// ---------------------------------------------------------------------------
// k4: per-batch softmax over t, then doc[b][i] = sum_t alpha[t]*h[t][b][i]
// ---------------------------------------------------------------------------
__global__ __launch_bounds__(128) void k4_doc(
    const float* __restrict__ h, const float* __restrict__ scT,
    float* __restrict__ out)
{
    const int b = blockIdx.x;
    const int tid = threadIdx.x;
    __shared__ float al[SEQ];
    __shared__ float red[128];

    float4 sv = reinterpret_cast<const float4*>(scT + (long)b * SEQ)[tid];
    float m = fmaxf(fmaxf(sv.x, sv.y), fmaxf(sv.z, sv.w));
    red[tid] = m;
    __syncthreads();
    if (tid < 64) red[tid] = fmaxf(red[tid], red[tid + 64]);
    __syncthreads();
    if (tid < 64) {
        float v = red[tid];
        for (int o = 32; o > 0; o >>= 1) v = fmaxf(v, __shfl_down(v, o));
        if (tid == 0) red[0] = v;
    }
    __syncthreads();
    m = red[0];
    float e0 = __expf(sv.x - m), e1 = __expf(sv.y - m);
    float e2 = __expf(sv.z - m), e3 = __expf(sv.w - m);
    float psum = e0 + e1 + e2 + e3;
    __syncthreads();
    red[tid] = psum;
    __syncthreads();
    if (tid < 64) red[tid] += red[tid + 64];
    __syncthreads();
    if (tid < 64) {
        float v = red[tid];
        for (int o = 32; o > 0; o >>= 1) v += __shfl_down(v, o);
        if (tid == 0) red[0] = v;
    }
    __syncthreads();
    const float inv = 1.f / red[0];
    al[tid * 4 + 0] = e0 * inv;
    al[tid * 4 + 1] = e1 * inv;
    al[tid * 4 + 2] = e2 * inv;
    al[tid * 4 + 3] = e3 * inv;
    __syncthreads();

    if (tid < MLPN) {
        float acc = 0.f;
        for (int t = 0; t < SEQ; t++)
            acc += al[t] * h[((long)t * BATCH + b) * 100 + tid];
        out[(long)b * 100 + tid] = acc;
    }
}

// ---------------------------------------------------------------------------
extern "C" void kernel_launch(void* const* d_in, const int* in_sizes, int n_in,
                              void* d_out, int out_size, void* d_ws, size_t ws_size,
                              hipStream_t stream)
{
    const int*   tokens = (const int*)d_in[0];
    const float* emb    = (const float*)d_in[1];
    const float* Wih_f  = (const float*)d_in[2];
    const float* Whh_f  = (const float*)d_in[3];
    const float* bih_f  = (const float*)d_in[4];
    const float* bhh_f  = (const float*)d_in[5];
    const float* Wih_b  = (const float*)d_in[6];
    const float* Whh_b  = (const float*)d_in[7];
    const float* bih_b  = (const float*)d_in[8];
    const float* bhh_b  = (const float*)d_in[9];
    const float* W_mlp  = (const float*)d_in[10];
    const float* b_mlp  = (const float*)d_in[11];
    const float* ctx    = (const float*)d_in[12];
    float* out = (float*)d_out;

    float* gx  = (float*)d_ws;                         // SEQ*BATCH*300
    float* h   = gx + (size_t)SEQ * BATCH * 300;       // SEQ*BATCH*100
    float* scT = h  + (size_t)SEQ * BATCH * 100;       // BATCH*SEQ
    unsigned short* Wpad = (unsigned short*)scT;       // aliased, dead before k3

    k0_wpad<<<280, 256, 0, stream>>>(Wih_f, Wih_b, Wpad);
    k1_gx<<<2048, 256, 0, stream>>>(tokens, emb, Wpad, bih_f, bih_b, gx);
    k2_gru<<<512, 64, 0, stream>>>(gx, Whh_f, bhh_f, Whh_b, bhh_b, h);
    k3_scores<<<512, 256, 0, stream>>>(h, W_mlp, b_mlp, ctx, scT);
    k4_doc<<<256, 128, 0, stream>>>(h, scT, out);
}

// Round 7
// 596.040 us; speedup vs baseline: 1.0454x; 1.0426x over previous
//
#include <hip/hip_runtime.h>
#include <hip/hip_bf16.h>

#define SEQ   512
#define BATCH 256
#define EMB   200
#define HID   50
#define G3    150     // 3*HID
#define MLPN  100

typedef __attribute__((ext_vector_type(8))) short bf16x8;
typedef __attribute__((ext_vector_type(4))) float f32x4;
typedef __attribute__((ext_vector_type(16))) float f32x16;

__device__ __forceinline__ unsigned short f2bf(float x) {
    unsigned u = __float_as_uint(x);
    unsigned r = (u + 0x7FFFu + ((u >> 16) & 1u)) >> 16;   // RNE
    return (unsigned short)r;
}

#define GLOAD_LDS16(g, s) __builtin_amdgcn_global_load_lds( \
    (const __attribute__((address_space(1))) void*)(g),     \
    (__attribute__((address_space(3))) void*)(s), 16, 0, 0)

// ---------------------------------------------------------------------------
// k0: convert Wih_f/Wih_b fp32 -> bf16 into padded layout Wpad[320][224]
// ---------------------------------------------------------------------------
__global__ __launch_bounds__(256) void k0_wpad(
    const float* __restrict__ Wih_f, const float* __restrict__ Wih_b,
    unsigned short* __restrict__ Wpad)
{
    int idx = blockIdx.x * 256 + threadIdx.x;
    if (idx >= 320 * 224) return;
    int row = idx / 224;
    int k   = idx - row * 224;
    int d   = row / 160;
    int r   = row - d * 160;
    float v = 0.f;
    if (r < G3 && k < EMB) v = (d ? Wih_b : Wih_f)[r * EMB + k];
    Wpad[idx] = f2bf(v);
}

// ---------------------------------------------------------------------------
// k1: gx = emb[tok] @ [Wih_f;Wih_b].T + bias, via bf16 MFMA 16x16x32.
// ---------------------------------------------------------------------------
__global__ __launch_bounds__(256) void k1_gx(
    const int* __restrict__ tokens, const float* __restrict__ emb,
    const unsigned short* __restrict__ Wpad,
    const float* __restrict__ bih_f, const float* __restrict__ bih_b,
    float* __restrict__ gx)
{
    __shared__ unsigned short Abuf[64 * 32];    // 4 KB
    __shared__ unsigned short Bbuf[320 * 32];   // 20 KB
    __shared__ float bias[320];
    __shared__ int tok[64];

    const int t = threadIdx.x;
    const int w = t >> 6;
    const int l = t & 63;
    const long row0 = (long)blockIdx.x * 64;

    for (int idx = t; idx < 320; idx += 256) {
        int d = idx / 160, r = idx - d * 160;
        bias[idx] = (r < G3) ? (d ? bih_b[r] : bih_f[r]) : 0.f;
    }
    if (t < 64) tok[t] = tokens[row0 + t];

    f32x4 acc[20];
    #pragma unroll
    for (int nt = 0; nt < 20; nt++) acc[nt] = (f32x4){0.f, 0.f, 0.f, 0.f};

    const int ar = t >> 2;
    const int kq = t & 3;
    __syncthreads();

    for (int c = 0; c < 7; c++) {
        const int kc0 = c * 32;
        float4 v0 = {0,0,0,0}, v1 = {0,0,0,0};
        if (kc0 + kq * 8 < EMB) {
            const float* src = emb + (long)tok[ar] * EMB + kc0 + kq * 8;
            v0 = *reinterpret_cast<const float4*>(src);
            v1 = *reinterpret_cast<const float4*>(src + 4);
        }
        __syncthreads();
        unsigned p0 = f2bf(v0.x) | ((unsigned)f2bf(v0.y) << 16);
        unsigned p1 = f2bf(v0.z) | ((unsigned)f2bf(v0.w) << 16);
        unsigned p2 = f2bf(v1.x) | ((unsigned)f2bf(v1.y) << 16);
        unsigned p3 = f2bf(v1.z) | ((unsigned)f2bf(v1.w) << 16);
        *reinterpret_cast<uint2*>(&Abuf[ar * 32 + kq * 8])     = make_uint2(p0, p1);
        *reinterpret_cast<uint2*>(&Abuf[ar * 32 + kq * 8 + 4]) = make_uint2(p2, p3);
        #pragma unroll
        for (int q = 0; q < 5; q++) {
            const int rbase = w * 80 + q * 16;
            const int rb = rbase + (l >> 2);
            const unsigned short* gsrc = Wpad + (long)rb * 224 + kc0 + (l & 3) * 8;
            GLOAD_LDS16(gsrc, &Bbuf[rbase * 32]);
        }
        __syncthreads();
        bf16x8 af = *reinterpret_cast<bf16x8*>(&Abuf[(w * 16 + (l & 15)) * 32 + (l >> 4) * 8]);
        #pragma unroll
        for (int nt = 0; nt < 20; nt++) {
            bf16x8 bfr = *reinterpret_cast<bf16x8*>(&Bbuf[(nt * 16 + (l & 15)) * 32 + (l >> 4) * 8]);
            acc[nt] = __builtin_amdgcn_mfma_f32_16x16x32_bf16(af, bfr, acc[nt], 0, 0, 0);
        }
    }

    const int colL  = l & 15;
    const int rquad = l >> 4;
    #pragma unroll
    for (int nt = 0; nt < 20; nt++) {
        int pcol = nt * 16 + colL;
        int d = pcol / 160;
        int jc = pcol - d * 160;
        if (jc >= G3) continue;
        float bv = bias[pcol];
        long col = d * G3 + jc;
        #pragma unroll
        for (int i = 0; i < 4; i++) {
            long row = row0 + w * 16 + rquad * 4 + i;
            gx[row * 300 + col] = acc[nt][i] + bv;
        }
    }
}

// ---------------------------------------------------------------------------
// k2: GRU scan — 3 waves per (batch,dir) chain; wave w owns gate w (r/z/n),
// lane l owns Whh row w*50+l => only 50 weights/lane (3 f32x16 + 2 scalars).
// Per step: all lanes 50-FMA chain from LDS-broadcast h (clean k-indexed
// unroll, acc3[k%3] constant-indexed => SSA); waves z,n post raw gh to LDS;
// barrier; wave r fuses gates + writes new h; barrier.
// ---------------------------------------------------------------------------
#define K2_LOAD(S, VR, VZ, VN) do {                                        \
    int t_ = dir ? (SEQ - 1 - (S)) : (S);                                  \
    const float* p_ = gx + (long)t_ * (BATCH * 300) + base;                \
    VR = p_[0]; VZ = p_[50]; VN = p_[100];                                 \
} while (0)

#define K2_STEP(S, VR, VZ, VN) do {                                        \
    const int t_ = dir ? (SEQ - 1 - (S)) : (S);                            \
    float acc3_[3] = {0.f, 0.f, 0.f};                                      \
    _Pragma("unroll")                                                      \
    for (int q_ = 0; q_ < 13; q_++) {                                      \
        const float4 hq_ = reinterpret_cast<float4*>(hs)[q_];              \
        _Pragma("unroll")                                                  \
        for (int r_ = 0; r_ < 4; r_++) {                                   \
            const int k_ = 4 * q_ + r_;                                    \
            if (k_ < 50) {                                                 \
                const float hk_ = (r_ == 0) ? hq_.x : (r_ == 1) ? hq_.y    \
                                : (r_ == 2) ? hq_.z : hq_.w;               \
                const float wk_ = (k_ < 16) ? w0[k_ & 15]                  \
                                : (k_ < 32) ? w1[k_ & 15]                  \
                                : (k_ < 48) ? w2[k_ & 15]                  \
                                : (k_ == 48) ? w48 : w49;                  \
                acc3_[k_ % 3] = fmaf(wk_, hk_, acc3_[k_ % 3]);             \
            }                                                              \
        }                                                                  \
    }                                                                      \
    const float acc_ = bj + ((acc3_[0] + acc3_[1]) + acc3_[2]);            \
    if (wv) { if (act) gzn[(wv - 1) * HID + l] = acc_; }                   \
    else if ((S) + 2 < SEQ) K2_LOAD((S) + 2, VR, VZ, VN);                  \
    __syncthreads();                                                       \
    if (wv == 0) {                                                         \
        const float ghz_ = gzn[lc], ghn_ = gzn[HID + lc];                  \
        const float r_ = 1.f / (1.f + __expf(-(VR + acc_)));               \
        const float z_ = 1.f / (1.f + __expf(-(VZ + ghz_)));               \
        const float x_ = VN + r_ * ghn_;                                   \
        const float e2_ = __expf(-2.f * x_);                               \
        const float n_ = (1.f - e2_) / (1.f + e2_);                        \
        hold = (1.f - z_) * n_ + z_ * hold;                                \
        if (act) {                                                         \
            hs[l] = hold;                                                  \
            h[((long)t_ * BATCH + b) * 100 + dir * HID + l] = hold;        \
        }                                                                  \
    }                                                                      \
    __syncthreads();                                                       \
} while (0)

__global__ __launch_bounds__(192, 2) void k2_gru(
    const float* __restrict__ gx,
    const float* __restrict__ Whh_f, const float* __restrict__ bhh_f,
    const float* __restrict__ Whh_b, const float* __restrict__ bhh_b,
    float* __restrict__ h)
{
    const int b   = blockIdx.x & 255;
    const int dir = blockIdx.x >> 8;
    const float* __restrict__ Whh = dir ? Whh_b : Whh_f;
    const float* __restrict__ bhh = dir ? bhh_b : bhh_f;
    const int tid = threadIdx.x;
    const int wv  = tid >> 6;              // 0=r, 1=z, 2=n  (wave-uniform)
    const int l   = tid & 63;
    const bool act = (l < HID);
    const int lc  = act ? l : (HID - 1);   // clamp: uniform loads
    const int row = wv * HID + lc;

    __shared__ alignas(16) float hs[52];
    __shared__ float gzn[2 * HID];

    const float* W = Whh + (long)row * HID;
    f32x16 w0, w1, w2;
    #pragma unroll
    for (int k = 0; k < 16; k++) {
        w0[k] = W[k]; w1[k] = W[16 + k]; w2[k] = W[32 + k];
    }
    const float w48 = W[48], w49 = W[49];
    const float bj = bhh[row];

    if (tid < 52) hs[tid] = 0.f;           // incl. 2 pad slots
    float hold = 0.f;

    const long base = (long)b * 300 + dir * G3 + lc;
    float p0r = 0.f, p0z = 0.f, p0n = 0.f, p1r = 0.f, p1z = 0.f, p1n = 0.f;
    if (wv == 0) {
        K2_LOAD(0, p0r, p0z, p0n);
        K2_LOAD(1, p1r, p1z, p1n);
    }
    __syncthreads();

    for (int s = 0; s < SEQ; s += 2) {
        K2_STEP(s,     p0r, p0z, p0n);
        K2_STEP(s + 1, p1r, p1z, p1n);
    }
}

// ---------------------------------------------------------------------------
// k3: scores via thread-per-row; W_mlp in LDS, h row in registers.
// ---------------------------------------------------------------------------
__global__ __launch_bounds__(256) void k3_scores(
    const float* __restrict__ h, const float* __restrict__ W_mlp,
    const float* __restrict__ b_mlp, const float* __restrict__ ctx,
    float* __restrict__ scT)
{
    __shared__ float4 Wm[MLPN * 25];
    __shared__ float bm[MLPN], cx[MLPN];
    const int tid = threadIdx.x;
    for (int idx = tid; idx < MLPN * 25; idx += 256)
        Wm[idx] = reinterpret_cast<const float4*>(W_mlp)[idx];
    if (tid < MLPN) { bm[tid] = b_mlp[tid]; cx[tid] = ctx[tid]; }
    __syncthreads();

    const long row = (long)blockIdx.x * 256 + tid;
    float4 hr[25];
    const float4* hp = reinterpret_cast<const float4*>(h + row * 100);
    #pragma unroll
    for (int i = 0; i < 25; i++) hr[i] = hp[i];

    float s = 0.f;
    for (int jj = 0; jj < MLPN; jj++) {
        float acc = bm[jj];
        #pragma unroll
        for (int i = 0; i < 25; i++) {
            float4 wv = Wm[jj * 25 + i];
            acc += wv.x * hr[i].x + wv.y * hr[i].y + wv.z * hr[i].z + wv.w * hr[i].w;
        }
        float e2 = __expf(-2.f * acc);
        float u = (1.f - e2) / (1.f + e2);
        s += u * cx[jj];
    }
    const int t = (int)(row >> 8);
    const int b = (int)(row & 255);
    scT[(long)b * SEQ + t] = s;
}

// ---------------------------------------------------------------------------
// k4: per-batch softmax over t, then doc[b][i] = sum_t alpha[t]*h[t][b][i]
// ---------------------------------------------------------------------------
__global__ __launch_bounds__(128) void k4_doc(
    const float* __restrict__ h, const float* __restrict__ scT,
    float* __restrict__ out)
{
    const int b = blockIdx.x;
    const int tid = threadIdx.x;
    __shared__ float al[SEQ];
    __shared__ float red[128];

    float4 sv = reinterpret_cast<const float4*>(scT + (long)b * SEQ)[tid];
    float m = fmaxf(fmaxf(sv.x, sv.y), fmaxf(sv.z, sv.w));
    red[tid] = m;
    __syncthreads();
    if (tid < 64) red[tid] = fmaxf(red[tid], red[tid + 64]);
    __syncthreads();
    if (tid < 64) {
        float v = red[tid];
        for (int o = 32; o > 0; o >>= 1) v = fmaxf(v, __shfl_down(v, o));
        if (tid == 0) red[0] = v;
    }
    __syncthreads();
    m = red[0];
    float e0 = __expf(sv.x - m), e1 = __expf(sv.y - m);
    float e2 = __expf(sv.z - m), e3 = __expf(sv.w - m);
    float psum = e0 + e1 + e2 + e3;
    __syncthreads();
    red[tid] = psum;
    __syncthreads();
    if (tid < 64) red[tid] += red[tid + 64];
    __syncthreads();
    if (tid < 64) {
        float v = red[tid];
        for (int o = 32; o > 0; o >>= 1) v += __shfl_down(v, o);
        if (tid == 0) red[0] = v;
    }
    __syncthreads();
    const float inv = 1.f / red[0];
    al[tid * 4 + 0] = e0 * inv;
    al[tid * 4 + 1] = e1 * inv;
    al[tid * 4 + 2] = e2 * inv;
    al[tid * 4 + 3] = e3 * inv;
    __syncthreads();

    if (tid < MLPN) {
        float acc = 0.f;
        for (int t = 0; t < SEQ; t++)
            acc += al[t] * h[((long)t * BATCH + b) * 100 + tid];
        out[(long)b * 100 + tid] = acc;
    }
}

// ---------------------------------------------------------------------------
extern "C" void kernel_launch(void* const* d_in, const int* in_sizes, int n_in,
                              void* d_out, int out_size, void* d_ws, size_t ws_size,
                              hipStream_t stream)
{
    const int*   tokens = (const int*)d_in[0];
    const float* emb    = (const float*)d_in[1];
    const float* Wih_f  = (const float*)d_in[2];
    const float* Whh_f  = (const float*)d_in[3];
    const float* bih_f  = (const float*)d_in[4];
    const float* bhh_f  = (const float*)d_in[5];
    const float* Wih_b  = (const float*)d_in[6];
    const float* Whh_b  = (const float*)d_in[7];
    const float* bih_b  = (const float*)d_in[8];
    const float* bhh_b  = (const float*)d_in[9];
    const float* W_mlp  = (const float*)d_in[10];
    const float* b_mlp  = (const float*)d_in[11];
    const float* ctx    = (const float*)d_in[12];
    float* out = (float*)d_out;

    float* gx  = (float*)d_ws;                         // SEQ*BATCH*300
    float* h   = gx + (size_t)SEQ * BATCH * 300;       // SEQ*BATCH*100
    float* scT = h  + (size_t)SEQ * BATCH * 100;       // BATCH*SEQ
    unsigned short* Wpad = (unsigned short*)scT;       // aliased, dead before k3

    k0_wpad<<<280, 256, 0, stream>>>(Wih_f, Wih_b, Wpad);
    k1_gx<<<2048, 256, 0, stream>>>(tokens, emb, Wpad, bih_f, bih_b, gx);
    k2_gru<<<512, 192, 0, stream>>>(gx, Whh_f, bhh_f, Whh_b, bhh_b, h);
    k3_scores<<<512, 256, 0, stream>>>(h, W_mlp, b_mlp, ctx, scT);
    k4_doc<<<256, 128, 0, stream>>>(h, scT, out);
}